// Round 2
// baseline (93.623 us; speedup 1.0000x reference)
//
#include <hip/hip_runtime.h>
#include <math.h>

#define N_   1024
#define IN_  512
#define OUT_ 256
#define E_   3

// ---------------------------------------------------------------------------
// Fused setup kernel. Grid: OUT_ blocks (one per output node o), 256 threads
// (thread = input index i, 2 i's per thread). Each thread redundantly computes
// the operator choice p = argmax_p(op_logit + gumbel) (wave-uniform, cheap),
// then for its i's picks the winning edge type e* = argmax_e at that p and
// stores packed bf16 coefficients (a, b) such that  s * edge_value = a*x + b,
// where s = +1 for T-norm (min) and -1 for T-conorm (max):
//   e*=0 (identity):   val = x       -> a =  s, b = 0
//   e*=1 (complement): val = 1 - x   -> a = -s, b = s
//   e*=2 (no_edge):    val = neutral -> a = 0,  b = s * neutral
//       neutral = 1 for T-norm, 0 for T-conorm  ->  b = s*1 = 1 or  -1*0 = 0... 
//       (computed explicitly below; all values in {0, +-1}, exact in bf16)
// Loads are coalesced: consecutive threads read consecutive 12-byte triplets.
// coefT layout [IN][OUT] so the main kernel's per-step load is coalesced.
// ---------------------------------------------------------------------------
__global__ __launch_bounds__(256) void setup_kernel(
        const float* __restrict__ edge_logits,  // [OUT, 2, IN, 3]
        const float* __restrict__ op_logits,    // [OUT, 2]
        const float* __restrict__ u_edge,       // [OUT, 2, IN, 3]
        const float* __restrict__ u_op,         // [OUT, 2]
        unsigned int* __restrict__ coefT,       // [IN, OUT] packed bf16x2 (a,b)
        float* __restrict__ signv) {            // [OUT]
    int o = blockIdx.x;
    int t = threadIdx.x;

    // operator pick (wave-uniform)
    float s0 = op_logits[o * 2 + 0] - logf(-logf(u_op[o * 2 + 0]));
    float s1 = op_logits[o * 2 + 1] - logf(-logf(u_op[o * 2 + 1]));
    int p = (s1 > s0) ? 1 : 0;               // first index wins ties (jnp.argmax)
    float s       = (p == 0) ? 1.0f : -1.0f;
    float neutral = (p == 0) ? 1.0f : 0.0f;
    if (t == 0) signv[o] = s;

    long rowbase = ((long)(o * 2 + p)) * IN_ * E_;

#pragma unroll
    for (int rep = 0; rep < IN_ / 256; ++rep) {
        int i = t + rep * 256;
        long base = rowbase + (long)i * E_;

        float best = -1e30f;
        int be = 0;
#pragma unroll
        for (int e = 0; e < E_; ++e) {
            float sc = edge_logits[base + e] - logf(-logf(u_edge[base + e]));
            if (sc > best) { best = sc; be = e; }
        }
        float a, b;
        if (be == 0)      { a = s;    b = 0.0f;       }
        else if (be == 1) { a = -s;   b = s;          }
        else              { a = 0.0f; b = s * neutral; }

        unsigned int ua = (__float_as_uint(a) >> 16);
        unsigned int ub = (__float_as_uint(b) & 0xffff0000u);
        coefT[i * OUT_ + o] = ua | ub;
    }
}

// ---------------------------------------------------------------------------
// Main kernel. One thread per output node o (256 threads/block), NPB=4
// consecutive n-rows per block, full I sweep per block (no split, no reduce
// kernel, final output written directly with the sign folded back).
// x tile staged in LDS transposed [ii][r] so the inner loop reads it with a
// wave-uniform broadcast ds_read_b128 (conflict-free).
// acc[r] = min over i of (a*x+b); init 2.0 (> any |s*val| <= 1).
// ---------------------------------------------------------------------------
#define NPB 4
__global__ __launch_bounds__(256) void main_kernel(
        const float* __restrict__ x,            // [N, IN]
        const unsigned int* __restrict__ coefT, // [IN, OUT]
        const float* __restrict__ signv,        // [OUT]
        float* __restrict__ out) {              // [N, OUT]
    int tid = threadIdx.x;
    int n0 = blockIdx.x * NPB;

    __shared__ float xT[IN_ * NPB];

    // cooperative transpose-stage: coalesced global reads
    for (int k = tid; k < IN_ * NPB; k += 256) {
        int r = k >> 9;          // k / IN_
        int ii = k & (IN_ - 1);  // k % IN_
        xT[ii * NPB + r] = x[(n0 + r) * IN_ + ii];
    }
    __syncthreads();

    float acc[NPB];
#pragma unroll
    for (int r = 0; r < NPB; ++r) acc[r] = 2.0f;

    const unsigned int* cp = coefT + tid;

#pragma unroll 8
    for (int ii = 0; ii < IN_; ++ii) {
        unsigned int c = cp[ii * OUT_];
        float a = __uint_as_float(c << 16);
        float b = __uint_as_float(c & 0xffff0000u);
        float4 xv = *(const float4*)&xT[ii * NPB];
        acc[0] = fminf(acc[0], fmaf(a, xv.x, b));
        acc[1] = fminf(acc[1], fmaf(a, xv.y, b));
        acc[2] = fminf(acc[2], fmaf(a, xv.z, b));
        acc[3] = fminf(acc[3], fmaf(a, xv.w, b));
    }

    float s = signv[tid];
#pragma unroll
    for (int r = 0; r < NPB; ++r)
        out[(n0 + r) * OUT_ + tid] = s * acc[r];
}

extern "C" void kernel_launch(void* const* d_in, const int* in_sizes, int n_in,
                              void* d_out, int out_size, void* d_ws, size_t ws_size,
                              hipStream_t stream) {
    const float* x           = (const float*)d_in[0];
    const float* edge_logits = (const float*)d_in[1];
    const float* op_logits   = (const float*)d_in[2];
    const float* u_edge      = (const float*)d_in[3];
    const float* u_op        = (const float*)d_in[4];
    float* out = (float*)d_out;

    char* ws = (char*)d_ws;
    unsigned int* coefT = (unsigned int*)(ws);                       // 512 KB
    float* signv        = (float*)(ws + (size_t)IN_ * OUT_ * 4);     // 1 KB

    setup_kernel<<<OUT_, 256, 0, stream>>>(edge_logits, op_logits, u_edge, u_op,
                                           coefT, signv);
    main_kernel<<<N_ / NPB, 256, 0, stream>>>(x, coefT, signv, out);
}